// Round 6
// baseline (231.702 us; speedup 1.0000x reference)
//
#include <hip/hip_runtime.h>

#define N_NODES 4096
#define F_UAV 64
#define NOBS 262400
#define GCN_FLAT (N_NODES * F_UAV)   // 262144
#define HDIM 1024
#define N_ACT 64
#define N_EDGES 65536

typedef float f32x4 __attribute__((ext_vector_type(4)));
typedef float f32x2 __attribute__((ext_vector_type(2)));

// matvec1 partition: 2048 blocks, first 256 take 129 rows, rest 128.
#define MV1_GRID 2048
#define MV1_BIGN 256
#define MV1_BIG 129
#define MV1_SMALL 128

// ---- workspace layout (float offsets). x and deg adjacent -> single memset.
#define OFF_X      0                          // 262400 floats
#define OFF_DEG    262400                     // 4096 ints
#define OFF_H      (OFF_DEG + N_NODES)        // 262144
#define OFF_P1     (OFF_H + GCN_FLAT)         // 2048*1024
#define OFF_Q1T    (OFF_P1 + 2048*1024)       // 1024*128
#define OFF_P2     (OFF_Q1T + 1024*128)       // 64*1024

// h = node_x @ gcn_w (4096x64 @ 64x64); blocks <256 also count edge in-degrees
// (deg[] pre-zeroed by the memset).
__global__ __launch_bounds__(256) void k_gcn_h(const float* __restrict__ nx,
                                               const float* __restrict__ w,
                                               const int* __restrict__ dst,
                                               float* __restrict__ h,
                                               int* __restrict__ deg) {
    __shared__ float sw[F_UAV * F_UAV];
    __shared__ float sx4[256];
    int tid = threadIdx.x;
    for (int i = tid; i < F_UAV * F_UAV; i += 256) sw[i] = w[i];
    sx4[tid] = nx[blockIdx.x * 256 + tid];
    if (blockIdx.x < 256) atomicAdd(&deg[dst[blockIdx.x * 256 + tid]], 1);
    __syncthreads();
    int r = tid >> 6, j = tid & 63;
    float acc = 0.f;
#pragma unroll
    for (int k = 0; k < F_UAV; ++k) acc += sx4[r * 64 + k] * sw[k * F_UAV + j];
    h[blockIdx.x * 256 + r * 64 + j] = acc;
}

// fused GCN aggregate into zeroed x:
//   blocks [0,16384): one wave per edge, atomicAdd messages
//   blocks [16384,16640): self-loop term + bias (4 elements/thread)
//   block 16640: obs tail copy
__global__ __launch_bounds__(256) void k_scatter_all(const int* __restrict__ src,
                                                     const int* __restrict__ dst,
                                                     const int* __restrict__ deg,
                                                     const float* __restrict__ h,
                                                     const float* __restrict__ gb,
                                                     const float* __restrict__ obs,
                                                     float* __restrict__ x) {
    int b = blockIdx.x;
    int tid = threadIdx.x;
    if (b < N_EDGES / 4) {
        int e = b * 4 + (tid >> 6);
        int j = tid & 63;
        int s = src[e], d = dst[e];
        float norm = rsqrtf((deg[s] + 1.0f) * (deg[d] + 1.0f));
        atomicAdd(&x[d * 64 + j], h[s * 64 + j] * norm);
    } else if (b < N_EDGES / 4 + 256) {
        int base = (b - N_EDGES / 4) * 1024 + tid * 4;
        int n = base >> 6;
        float dinv2 = 1.0f / (float)(deg[n] + 1);
#pragma unroll
        for (int u = 0; u < 4; ++u) {
            int idx = base + u;
            atomicAdd(&x[idx], h[idx] * dinv2 + gb[idx & 63]);
        }
    } else {
        if (tid < NOBS - GCN_FLAT) x[GCN_FLAT + tid] = obs[GCN_FLAT + tid];
    }
}

// partial mat-vec, ragged block row-ranges (tail-free grid).
__global__ __launch_bounds__(256) void k_matvec(const float* __restrict__ x,
                                                const float* __restrict__ W,
                                                float* __restrict__ part,
                                                int big_n, int big_sz, int small_sz) {
    __shared__ float sx[132];
    int tid = threadIdx.x;
    int b = blockIdx.x;
    int k0 = (b < big_n) ? b * big_sz : big_n * big_sz + (b - big_n) * small_sz;
    int cnt = (b < big_n) ? big_sz : small_sz;
    for (int i = tid; i < cnt; i += 256) sx[i] = x[k0 + i];
    __syncthreads();
    f32x4 acc = {0.f, 0.f, 0.f, 0.f};
    const f32x4* Wr = ((const f32x4*)W) + (size_t)k0 * (HDIM / 4) + tid;
    int kk = cnt & ~7;
    int k = 0;
    for (; k < kk; k += 8) {
#pragma unroll
        for (int u = 0; u < 8; ++u) {
            float xv = sx[k + u];
            f32x4 w = __builtin_nontemporal_load(&Wr[(size_t)(k + u) * (HDIM / 4)]);
            acc += xv * w;
        }
    }
    for (; k < cnt; ++k) acc += sx[k] * __builtin_nontemporal_load(&Wr[(size_t)k * (HDIM / 4)]);
    ((f32x4*)(part + (size_t)b * HDIM))[tid] = acc;
}

// stage-A: block s sums 16 consecutive partial rows, writes TRANSPOSED qT[j][s]
template <int NSEG>
__global__ __launch_bounds__(256) void k_sum16T(const float* __restrict__ part,
                                                float* __restrict__ qT) {
    int t = threadIdx.x, s = blockIdx.x;
    const f32x4* p = ((const f32x4*)part) + (size_t)s * 16 * (HDIM / 4) + t;
    f32x4 acc = {0.f, 0.f, 0.f, 0.f};
#pragma unroll
    for (int r = 0; r < 16; ++r) acc += p[(size_t)r * (HDIM / 4)];
#pragma unroll
    for (int u = 0; u < 4; ++u) qT[(size_t)(4 * t + u) * NSEG + s] = acc[u];
}

// fused: y1[16b..16b+16) = relu(b1 + rowsum of q1T), then 16-row matvec vs w2.
// 64 blocks x 256 threads.
__global__ __launch_bounds__(256) void k_fin_mv2(const float* __restrict__ q1T,
                                                 const float* __restrict__ b1,
                                                 const float* __restrict__ w2,
                                                 float* __restrict__ p2) {
    __shared__ float s_y[16];
    int t = threadIdx.x, b = blockIdx.x;
    int w = t >> 6, l = t & 63;
#pragma unroll
    for (int rr = 0; rr < 4; ++rr) {
        int j = 16 * b + 4 * w + rr;
        f32x2 v = *(const f32x2*)&q1T[(size_t)j * 128 + 2 * l];
        float sm = v.x + v.y;
        for (int off = 32; off; off >>= 1) sm += __shfl_xor(sm, off);
        if (l == 0) s_y[4 * w + rr] = fmaxf(b1[j] + sm, 0.f);
    }
    __syncthreads();
    f32x4 acc = {0.f, 0.f, 0.f, 0.f};
    const f32x4* Wr = ((const f32x4*)w2) + (size_t)(16 * b) * (HDIM / 4) + t;
#pragma unroll
    for (int i = 0; i < 16; ++i) acc += s_y[i] * Wr[(size_t)i * (HDIM / 4)];
    ((f32x4*)(p2 + (size_t)b * HDIM))[t] = acc;
}

// fused: y2 = relu(b2 + colsum of p2[64][1024]) then dueling heads. 1 block x 1024.
__global__ __launch_bounds__(1024) void k_heads_f(const float* __restrict__ p2,
                                                  const float* __restrict__ b2,
                                                  const float* __restrict__ wv,
                                                  const float* __restrict__ bv,
                                                  const float* __restrict__ wa,
                                                  const float* __restrict__ ba,
                                                  float* __restrict__ out) {
    __shared__ float y2s[1024];
    __shared__ float s_adv[16][64];
    __shared__ float s_pv[1024];
    int t = threadIdx.x;
    float acc = b2[t];
#pragma unroll 8
    for (int s = 0; s < 64; ++s) acc += p2[s * HDIM + t];
    float y = fmaxf(acc, 0.f);
    y2s[t] = y;
    s_pv[t] = y * wv[t];
    __syncthreads();
    int g = t >> 6, a = t & 63;
    float pa = 0.f;
#pragma unroll 4
    for (int kk = 0; kk < 64; ++kk) pa += y2s[g * 64 + kk] * wa[(g * 64 + kk) * 64 + a];
    s_adv[g][a] = pa;
    __syncthreads();
    if (t < 64) {
        float adv = ba[a];
#pragma unroll
        for (int gg = 0; gg < 16; ++gg) adv += s_adv[gg][a];
        float v = 0.f;
#pragma unroll
        for (int i = 0; i < 16; ++i) v += s_pv[a + 64 * i];
        for (int off = 32; off; off >>= 1) v += __shfl_xor(v, off);
        float m = adv;
        for (int off = 32; off; off >>= 1) m += __shfl_xor(m, off);
        m *= (1.f / 64.f);
        out[a] = (v + bv[0]) + adv - m;
    }
}

extern "C" void kernel_launch(void* const* d_in, const int* in_sizes, int n_in,
                              void* d_out, int out_size, void* d_ws, size_t ws_size,
                              hipStream_t stream) {
    const float* node_x   = (const float*)d_in[0];
    const float* flat_obs = (const float*)d_in[1];
    const float* gcn_w    = (const float*)d_in[2];
    const float* gcn_b    = (const float*)d_in[3];
    const float* w1       = (const float*)d_in[4];
    const float* b1       = (const float*)d_in[5];
    const float* w2       = (const float*)d_in[6];
    const float* b2       = (const float*)d_in[7];
    const float* wv       = (const float*)d_in[8];
    const float* bv       = (const float*)d_in[9];
    const float* wa       = (const float*)d_in[10];
    const float* ba       = (const float*)d_in[11];
    const int*   ei       = (const int*)d_in[12];
    const int* src = ei;
    const int* dst = ei + N_EDGES;

    float* ws   = (float*)d_ws;
    float* x    = ws + OFF_X;
    int*   deg  = (int*)(ws + OFF_DEG);
    float* h    = ws + OFF_H;
    float* p1   = ws + OFF_P1;
    float* q1T  = ws + OFF_Q1T;
    float* p2   = ws + OFF_P2;
    float* out  = (float*)d_out;

    // zero x (scatter target) and deg in one shot (adjacent)
    hipMemsetAsync(x, 0, (NOBS + N_NODES) * sizeof(float), stream);
    k_gcn_h<<<GCN_FLAT / 256, 256, 0, stream>>>(node_x, gcn_w, dst, h, deg);
    k_scatter_all<<<N_EDGES / 4 + 256 + 1, 256, 0, stream>>>(src, dst, deg, h,
                                                             gcn_b, flat_obs, x);

    k_matvec<<<MV1_GRID, 256, 0, stream>>>(x, w1, p1, MV1_BIGN, MV1_BIG, MV1_SMALL);
    k_sum16T<128><<<128, 256, 0, stream>>>(p1, q1T);
    k_fin_mv2<<<64, 256, 0, stream>>>(q1T, b1, w2, p2);
    k_heads_f<<<1, 1024, 0, stream>>>(p2, b2, wv, bv, wa, ba, out);
}